// Round 18
// baseline (611.193 us; speedup 1.0000x reference)
//
#include <hip/hip_runtime.h>
#include <hip/hip_bf16.h>
#include <string.h>

typedef __hip_bfloat16 bf16;
typedef short v8s __attribute__((ext_vector_type(8)));
typedef float v4f __attribute__((ext_vector_type(4)));

#define H_ 128
#define P_ 6
#define K_ 4

__device__ __forceinline__ float s2f(short s) {
    unsigned int u = ((unsigned int)(unsigned short)s) << 16;
    float f; __builtin_memcpy(&f, &u, 4); return f;
}
__device__ __forceinline__ short f2s(float v) {
    bf16 h = __float2bfloat16(v);
    short s; __builtin_memcpy(&s, &h, 2); return s;
}
__device__ __forceinline__ v4f MFMA(v8s a, v8s b, v4f c) {
    return __builtin_amdgcn_mfma_f32_16x16x32_bf16(a, b, c, 0, 0, 0);
}

// ---------------- merged prep: deg+adjb (rows), WT x8, WT2 x8, s1Wt ----------------
__global__ __launch_bounds__(128) void k_prep(const float* __restrict__ adj,
    float* __restrict__ degf, bf16* __restrict__ adjb,
    const float* __restrict__ iW1, const float* __restrict__ iW2,
    const float* __restrict__ glW1, const float* __restrict__ glW2,
    const float* __restrict__ in_W2, const float* __restrict__ gW1,
    const float* __restrict__ gW2, const float* __restrict__ s1_W,
    bf16* __restrict__ WT, bf16* __restrict__ WT2, bf16* __restrict__ s1Wt)
{
    __shared__ float red[128];
    const int b = blockIdx.x, t = threadIdx.x;
    if (b < 4096) {
        float a = adj[(size_t)b * 128 + t];
        adjb[(size_t)b * 128 + t] = __float2bfloat16(a);
        red[t] = a;
        __syncthreads();
        for (int s = 64; s > 0; s >>= 1) {
            if (t < s) red[t] += red[t + s];
            __syncthreads();
        }
        if (t == 0) degf[b] = red[0];
    } else if (b < 5120) {
        const int bb = b - 4096, w = bb >> 7, n = bb & 127;
        const float* arr[8] = {iW1, iW2, iW1 + 16384, iW2 + 16384,
                               glW1, glW2, glW1 + 16384, glW2 + 16384};
        WT[(size_t)w * 16384 + n * 128 + t] = __float2bfloat16(arr[w][t * 128 + n]);
    } else if (b < 6144) {
        const int bb = b - 5120, w = bb >> 7, n = bb & 127;
        const float* arr[8] = {in_W2, gW1, gW2, gW1 + 16384,
                               gW2 + 16384, gW1 + 32768, gW2 + 32768, in_W2};
        WT2[(size_t)w * 16384 + n * 128 + t] = __float2bfloat16(arr[w][t * 128 + n]);
    } else {
        const int n = b - 6144;
        s1Wt[n * 128 + t] = __float2bfloat16(s1_W[t * 128 + n]);
    }
}

// ---------------- FAT kernel: blocks <3072 = ID layer 1 (unchanged body);
// blocks >=3072 = h-pipeline (single-buffer gl-v2 discipline), graph = bid-3072.
// Independent work co-scheduled in one dispatch: the 32 h-blocks hide inside id1.
__global__ __launch_bounds__(256) void k_id1h(
    // id1 args
    const float* __restrict__ adj, const float* __restrict__ degf,
    const int* __restrict__ subgs, const int* __restrict__ allperm,
    const float* __restrict__ idemb, bf16* __restrict__ outb,
    const bf16* __restrict__ W1t, const float* __restrict__ b1,
    const bf16* __restrict__ W2t, const float* __restrict__ b2,
    const float* __restrict__ gam, const float* __restrict__ bet,
    // h args
    const float* __restrict__ x, const bf16* __restrict__ adjb,
    const float* __restrict__ inW1, const float* __restrict__ inb1,
    const bf16* __restrict__ inW2t, const float* __restrict__ inb2,
    const float* __restrict__ ing, const float* __restrict__ inbn,
    const bf16* __restrict__ WTg,
    const float* __restrict__ gb1, const float* __restrict__ gb2,
    const float* __restrict__ gg, const float* __restrict__ gbn,
    float* __restrict__ hb)
{
    __shared__ __align__(16) short sB[128][136];   // 34.8 KB (both branches)
    __shared__ float sP[15][128];                  //  7.7 KB (h params / id1 sE)
    const int t = threadIdx.x;
    const int wave = t >> 6, lane = t & 63, quad = lane >> 4, l16 = lane & 15;
    const int wrow = wave << 5;

    if (blockIdx.x < 3072) {
        // ================= ID layer 1 (byte-identical logic to passing R17) =================
        const int bi = blockIdx.x;
        const int b_s = bi / 6, p = bi - b_s * 6;
        const int g = b_s >> 4;
        float (*sE)[128] = sP;     // rows 0..3

        int nodeq[K_];
        #pragma unroll
        for (int q = 0; q < K_; ++q) nodeq[q] = subgs[b_s * K_ + q];

        for (int u = t; u < K_ * 128; u += 256) {
            const int q = u >> 7, f = u & 127;
            sE[q][f] = idemb[(size_t)allperm[q * P_ + p] * H_ + f] - 1.f;
        }
        __syncthreads();

        {
            const int i = t >> 1, half = (t & 1) * 64;
            const int gi = g * 128 + i;
            const float dg = degf[gi];
            float aq[K_];
            #pragma unroll
            for (int q = 0; q < K_; ++q) aq[q] = adj[(size_t)gi * 128 + nodeq[q]];
            #pragma unroll
            for (int f = 0; f < 64; ++f) {
                float v = dg;
                #pragma unroll
                for (int q = 0; q < K_; ++q) v = fmaf(aq[q], sE[q][half + f], v);
                sB[i][half + f] = f2s(v);
            }
        }
        __syncthreads();

        v4f acc[2][8];
        #pragma unroll
        for (int mt = 0; mt < 2; ++mt)
            #pragma unroll
            for (int nt = 0; nt < 8; ++nt) acc[mt][nt] = (v4f){0.f, 0.f, 0.f, 0.f};
        #pragma unroll
        for (int kk = 0; kk < 4; ++kk) {
            v8s a0 = *(const v8s*)&sB[wrow + l16][kk * 32 + quad * 8];
            v8s a1 = *(const v8s*)&sB[wrow + 16 + l16][kk * 32 + quad * 8];
            #pragma unroll
            for (int nt = 0; nt < 8; ++nt) {
                v8s b = *(const v8s*)(W1t + (nt * 16 + l16) * 128 + kk * 32 + quad * 8);
                acc[0][nt] = MFMA(a0, b, acc[0][nt]);
                acc[1][nt] = MFMA(a1, b, acc[1][nt]);
            }
        }
        #pragma unroll
        for (int nt = 0; nt < 8; ++nt) {
            float bb = b1[nt * 16 + l16];
            #pragma unroll
            for (int mt = 0; mt < 2; ++mt)
                #pragma unroll
                for (int r = 0; r < 4; ++r)
                    sB[wrow + mt * 16 + quad * 4 + r][nt * 16 + l16] = f2s(fmaxf(acc[mt][nt][r] + bb, 0.f));
        }
        #pragma unroll
        for (int mt = 0; mt < 2; ++mt)
            #pragma unroll
            for (int nt = 0; nt < 8; ++nt) acc[mt][nt] = (v4f){0.f, 0.f, 0.f, 0.f};
        #pragma unroll
        for (int kk = 0; kk < 4; ++kk) {
            v8s a0 = *(const v8s*)&sB[wrow + l16][kk * 32 + quad * 8];
            v8s a1 = *(const v8s*)&sB[wrow + 16 + l16][kk * 32 + quad * 8];
            #pragma unroll
            for (int nt = 0; nt < 8; ++nt) {
                v8s b = *(const v8s*)(W2t + (nt * 16 + l16) * 128 + kk * 32 + quad * 8);
                acc[0][nt] = MFMA(a0, b, acc[0][nt]);
                acc[1][nt] = MFMA(a1, b, acc[1][nt]);
            }
        }
        float bb2[8], gv[8], bv[8];
        #pragma unroll
        for (int nt = 0; nt < 8; ++nt) {
            int n = nt * 16 + l16;
            bb2[nt] = b2[n]; gv[nt] = gam[n]; bv[nt] = bet[n];
        }
        #pragma unroll
        for (int mt = 0; mt < 2; ++mt)
            #pragma unroll
            for (int r = 0; r < 4; ++r) {
                float s = 0.f, q = 0.f;
                #pragma unroll
                for (int nt = 0; nt < 8; ++nt) {
                    float u = acc[mt][nt][r] + bb2[nt];
                    acc[mt][nt][r] = u;
                    s += u; q += u * u;
                }
                #pragma unroll
                for (int d = 1; d < 16; d <<= 1) {
                    s += __shfl_xor(s, d);
                    q += __shfl_xor(q, d);
                }
                float mn = s * (1.f / 128.f);
                float rs = rsqrtf(q * (1.f / 128.f) - mn * mn + 1e-5f);
                #pragma unroll
                for (int nt = 0; nt < 8; ++nt) {
                    float v = fmaxf((acc[mt][nt][r] - mn) * rs * gv[nt] + bv[nt], 0.f);
                    sB[wrow + mt * 16 + quad * 4 + r][nt * 16 + l16] = f2s(v + 1.0f);
                }
            }
        __syncthreads();
        {
            const int f = t >> 1, nh = (t & 1) * 64;
            const short* flat = &sB[0][0];
            bf16* dst = outb + (size_t)bi * 16384 + (size_t)f * 128 + nh;
            #pragma unroll
            for (int u = 0; u < 8; ++u) {
                v8s pk;
                #pragma unroll
                for (int e = 0; e < 8; ++e) pk[e] = flat[(nh + u * 8 + e) * 136 + f];
                *(v8s*)(dst + u * 8) = pk;
            }
        }
        return;
    }

    // ================= h-pipeline (single-buffer gl-v2 discipline) =================
    const int g = blockIdx.x - 3072;

    for (int u = t; u < 15 * 128; u += 256) {
        const int a = u >> 7, n = u & 127;
        const float* src;
        if (a == 0) src = inb2;
        else if (a == 1) src = ing;
        else if (a == 2) src = inbn;
        else {
            const int l = (a - 3) >> 2, pp = (a - 3) & 3;
            src = (pp == 0) ? gb1 + l * 128 : (pp == 1) ? gb2 + l * 128
                : (pp == 2) ? gg + l * 128 : gbn + l * 128;
        }
        sP[a][n] = src[n];
    }

    v8s aA[2][4];
    {
        const bf16* ar = adjb + (size_t)g * 16384;
        #pragma unroll
        for (int mt = 0; mt < 2; ++mt)
            #pragma unroll
            for (int kk = 0; kk < 4; ++kk)
                aA[mt][kk] = *(const v8s*)(ar + (size_t)(wrow + mt * 16 + l16) * 128 + kk * 32 + quad * 8);
    }

    // t1 = relu(x*W1 + b1) into sB wave-own rows
    {
        const int i = t >> 1, half = (t & 1) * 64;
        const float xv = x[(size_t)g * 128 + i];
        #pragma unroll
        for (int fb = 0; fb < 64; fb += 8) {
            v8s pk;
            #pragma unroll
            for (int e = 0; e < 8; ++e)
                pk[e] = f2s(fmaxf(fmaf(xv, inW1[half + fb + e], inb1[half + fb + e]), 0.f));
            *(v8s*)&sB[i][half + fb] = pk;
        }
    }
    // h0 MM: reads wave-own rows of sB (same-wave writes visible)
    v4f acc[2][8];
    #pragma unroll
    for (int mt = 0; mt < 2; ++mt)
        #pragma unroll
        for (int nt = 0; nt < 8; ++nt) acc[mt][nt] = (v4f){0.f, 0.f, 0.f, 0.f};
    #pragma unroll
    for (int kk = 0; kk < 4; ++kk) {
        v8s a0 = *(const v8s*)&sB[wrow + l16][kk * 32 + quad * 8];
        v8s a1 = *(const v8s*)&sB[wrow + 16 + l16][kk * 32 + quad * 8];
        #pragma unroll
        for (int nt = 0; nt < 8; ++nt) {
            v8s b = *(const v8s*)(inW2t + (nt * 16 + l16) * 128 + kk * 32 + quad * 8);
            acc[0][nt] = MFMA(a0, b, acc[0][nt]);
            acc[1][nt] = MFMA(a1, b, acc[1][nt]);
        }
    }
    __syncthreads();                 // (X) all MM reads done; sP visible
    float hs_reg[2][8][4];
    #pragma unroll
    for (int mt = 0; mt < 2; ++mt)
        #pragma unroll
        for (int r = 0; r < 4; ++r) {
            float s = 0.f, qq = 0.f;
            #pragma unroll
            for (int nt = 0; nt < 8; ++nt) {
                float u = acc[mt][nt][r] + sP[0][nt * 16 + l16];
                acc[mt][nt][r] = u;
                s += u; qq += u * u;
            }
            #pragma unroll
            for (int d = 1; d < 16; d <<= 1) {
                s += __shfl_xor(s, d);
                qq += __shfl_xor(qq, d);
            }
            float mn = s * (1.f / 128.f);
            float rs = rsqrtf(qq * (1.f / 128.f) - mn * mn + 1e-5f);
            const int i = wrow + mt * 16 + quad * 4 + r;
            #pragma unroll
            for (int nt = 0; nt < 8; ++nt) {
                const int n = nt * 16 + l16;
                float v = fmaxf((acc[mt][nt][r] - mn) * rs * sP[1][n] + sP[2][n], 0.f);
                hs_reg[mt][nt][r] = v;
                sB[n][i] = f2s(v);
            }
        }
    __syncthreads();                 // (Y) h^T complete

    for (int l = 0; l < 3; ++l) {
        const bf16* W1t_ = WTg + (size_t)(2 * l) * 16384;
        const bf16* W2t_ = WTg + (size_t)(2 * l + 1) * 16384;
        #pragma unroll
        for (int mt = 0; mt < 2; ++mt)
            #pragma unroll
            for (int nt = 0; nt < 8; ++nt) acc[mt][nt] = (v4f){0.f, 0.f, 0.f, 0.f};
        #pragma unroll
        for (int kk = 0; kk < 4; ++kk)
            #pragma unroll
            for (int nt = 0; nt < 8; ++nt) {
                v8s b = *(const v8s*)&sB[nt * 16 + l16][kk * 32 + quad * 8];
                acc[0][nt] = MFMA(aA[0][kk], b, acc[0][nt]);
                acc[1][nt] = MFMA(aA[1][kk], b, acc[1][nt]);
            }
        __syncthreads();             // (A) spmv reads done; sB reusable as M/T
        #pragma unroll
        for (int nt = 0; nt < 8; ++nt)
            #pragma unroll
            for (int mt = 0; mt < 2; ++mt)
                #pragma unroll
                for (int r = 0; r < 4; ++r)
                    sB[wrow + mt * 16 + quad * 4 + r][nt * 16 + l16] = f2s(acc[mt][nt][r]);
        #pragma unroll
        for (int mt = 0; mt < 2; ++mt)
            #pragma unroll
            for (int nt = 0; nt < 8; ++nt) acc[mt][nt] = (v4f){0.f, 0.f, 0.f, 0.f};
        #pragma unroll
        for (int kk = 0; kk < 4; ++kk) {
            v8s a0 = *(const v8s*)&sB[wrow + l16][kk * 32 + quad * 8];
            v8s a1 = *(const v8s*)&sB[wrow + 16 + l16][kk * 32 + quad * 8];
            #pragma unroll
            for (int nt = 0; nt < 8; ++nt) {
                v8s b = *(const v8s*)(W1t_ + (nt * 16 + l16) * 128 + kk * 32 + quad * 8);
                acc[0][nt] = MFMA(a0, b, acc[0][nt]);
                acc[1][nt] = MFMA(a1, b, acc[1][nt]);
            }
        }
        #pragma unroll
        for (int nt = 0; nt < 8; ++nt) {
            float bb = sP[3 + 4 * l + 0][nt * 16 + l16];
            #pragma unroll
            for (int mt = 0; mt < 2; ++mt)
                #pragma unroll
                for (int r = 0; r < 4; ++r)
                    sB[wrow + mt * 16 + quad * 4 + r][nt * 16 + l16] = f2s(fmaxf(acc[mt][nt][r] + bb, 0.f));
        }
        #pragma unroll
        for (int mt = 0; mt < 2; ++mt)
            #pragma unroll
            for (int nt = 0; nt < 8; ++nt) acc[mt][nt] = (v4f){0.f, 0.f, 0.f, 0.f};
        #pragma unroll
        for (int kk = 0; kk < 4; ++kk) {
            v8s a0 = *(const v8s*)&sB[wrow + l16][kk * 32 + quad * 8];
            v8s a1 = *(const v8s*)&sB[wrow + 16 + l16][kk * 32 + quad * 8];
            #pragma unroll
            for (int nt = 0; nt < 8; ++nt) {
                v8s b = *(const v8s*)(W2t_ + (nt * 16 + l16) * 128 + kk * 32 + quad * 8);
                acc[0][nt] = MFMA(a0, b, acc[0][nt]);
                acc[1][nt] = MFMA(a1, b, acc[1][nt]);
            }
        }
        __syncthreads();             // (B) MM2 reads done before h^T scatter
        #pragma unroll
        for (int mt = 0; mt < 2; ++mt)
            #pragma unroll
            for (int r = 0; r < 4; ++r) {
                float s = 0.f, qq = 0.f;
                #pragma unroll
                for (int nt = 0; nt < 8; ++nt) {
                    float u = acc[mt][nt][r] + sP[3 + 4 * l + 1][nt * 16 + l16];
                    acc[mt][nt][r] = u;
                    s += u; qq += u * u;
                }
                #pragma unroll
                for (int d = 1; d < 16; d <<= 1) {
                    s += __shfl_xor(s, d);
                    qq += __shfl_xor(qq, d);
                }
                float mn = s * (1.f / 128.f);
                float rs = rsqrtf(qq * (1.f / 128.f) - mn * mn + 1e-5f);
                const int i = wrow + mt * 16 + quad * 4 + r;
                #pragma unroll
                for (int nt = 0; nt < 8; ++nt) {
                    const int n = nt * 16 + l16;
                    float v = fmaxf((acc[mt][nt][r] - mn) * rs * sP[3 + 4 * l + 2][n] + sP[3 + 4 * l + 3][n], 0.f);
                    float h2 = hs_reg[mt][nt][r] + v;
                    hs_reg[mt][nt][r] = h2;
                    sB[n][i] = f2s(h2);
                }
            }
        __syncthreads();             // (C) h^T complete
    }

    #pragma unroll
    for (int mt = 0; mt < 2; ++mt)
        #pragma unroll
        for (int nt = 0; nt < 8; ++nt)
            #pragma unroll
            for (int r = 0; r < 4; ++r) {
                const int i = wrow + mt * 16 + quad * 4 + r;
                const int n = nt * 16 + l16;
                hb[((size_t)(g * 128 + i)) * 128 + n] = hs_reg[mt][nt][r];
            }
}

// ---------------- ID layer 2 v9 (passing, R13) ----------------
__global__ __launch_bounds__(256) void k_id2_v9(
    const bf16* __restrict__ z2t, bf16* __restrict__ zm,
    const bf16* __restrict__ adjb, const int* __restrict__ num_node,
    const int* __restrict__ subgs, const int* __restrict__ allperm,
    const float* __restrict__ idemb,
    const bf16* __restrict__ W1t, const float* __restrict__ b1,
    const bf16* __restrict__ W2t, const float* __restrict__ b2,
    const float* __restrict__ gam, const float* __restrict__ bet)
{
    __shared__ __align__(16) short sB[128][136];
    __shared__ float sP[4][128];
    const int t = threadIdx.x;
    const int b_s = blockIdx.x;
    const int g = b_s >> 4;
    const int wave = t >> 6, lane = t & 63, quad = lane >> 4, l16 = lane & 15;
    const int wrow = wave << 5;

    #pragma unroll
    for (int u = 0; u < 2; ++u) {
        const int v = t + u * 256;
        const int a = v >> 7, n = v & 127;
        const float* src = (a == 0) ? b1 : (a == 1) ? b2 : (a == 2) ? gam : bet;
        sP[a][n] = src[n];
    }

    v8s aA[2][4];
    {
        const bf16* ar = adjb + (size_t)g * 16384;
        #pragma unroll
        for (int mt = 0; mt < 2; ++mt)
            #pragma unroll
            for (int kk = 0; kk < 4; ++kk)
                aA[mt][kk] = *(const v8s*)(ar + (size_t)(wrow + mt * 16 + l16) * 128 + kk * 32 + quad * 8);
    }
    int nodeq[K_];
    #pragma unroll
    for (int q = 0; q < K_; ++q) nodeq[q] = subgs[b_s * K_ + q];

    float macc[2][8][4];
    #pragma unroll
    for (int mt = 0; mt < 2; ++mt)
        #pragma unroll
        for (int nt = 0; nt < 8; ++nt)
            #pragma unroll
            for (int r = 0; r < 4; ++r) macc[mt][nt][r] = 0.f;

    const int sf = t >> 1, shalf = (t & 1) * 64;

    for (int p = 0; p < P_; ++p) {
        {
            const bf16* src = z2t + ((size_t)(b_s * P_ + p)) * 16384 + (size_t)sf * 128 + shalf;
            #pragma unroll
            for (int u = 0; u < 8; ++u)
                *(v8s*)&sB[sf][shalf + u * 8] = *(const v8s*)(src + u * 8);
        }
        __syncthreads();
        if (t < 128) {
            #pragma unroll
            for (int q = 0; q < K_; ++q) {
                float e = idemb[(size_t)allperm[q * P_ + p] * H_ + t] - 1.f;
                short* cell = &sB[t][nodeq[q]];
                *cell = f2s(s2f(*cell) + e);
            }
        }
        __syncthreads();
        #pragma unroll
        for (int mt = 0; mt < 2; ++mt)
            #pragma unroll
            for (int nt = 0; nt < 8; ++nt) {
                const int n = nt * 16 + l16;
                #pragma unroll
                for (int r = 0; r < 4; ++r)
                    macc[mt][nt][r] += s2f(sB[n][wrow + mt * 16 + quad * 4 + r]);
            }
        v4f acc[2][8];
        #pragma unroll
        for (int mt = 0; mt < 2; ++mt)
            #pragma unroll
            for (int nt = 0; nt < 8; ++nt) acc[mt][nt] = (v4f){0.f, 0.f, 0.f, 0.f};
        #pragma unroll
        for (int kk = 0; kk < 4; ++kk)
            #pragma unroll
            for (int nt = 0; nt < 8; ++nt) {
                v8s b = *(const v8s*)&sB[nt * 16 + l16][kk * 32 + quad * 8];
                acc[0][nt] = MFMA(aA[0][kk], b, acc[0][nt]);
                acc[1][nt] = MFMA(aA[1][kk], b, acc[1][nt]);
            }
        __syncthreads();
        #pragma unroll
        for (int nt = 0; nt < 8; ++nt)
            #pragma unroll
            for (int mt = 0; mt < 2; ++mt)
                #pragma unroll
                for (int r = 0; r < 4; ++r)
                    sB[wrow + mt * 16 + quad * 4 + r][nt * 16 + l16] = f2s(acc[mt][nt][r]);
        #pragma unroll
        for (int mt = 0; mt < 2; ++mt)
            #pragma unroll
            for (int nt = 0; nt < 8; ++nt) acc[mt][nt] = (v4f){0.f, 0.f, 0.f, 0.f};
        #pragma unroll
        for (int kk = 0; kk < 4; ++kk) {
            v8s a0 = *(const v8s*)&sB[wrow + l16][kk * 32 + quad * 8];
            v8s a1 = *(const v8s*)&sB[wrow + 16 + l16][kk * 32 + quad * 8];
            #pragma unroll
            for (int nt = 0; nt < 8; ++nt) {
                v8s b = *(const v8s*)(W1t + (nt * 16 + l16) * 128 + kk * 32 + quad * 8);
                acc[0][nt] = MFMA(a0, b, acc[0][nt]);
                acc[1][nt] = MFMA(a1, b, acc[1][nt]);
            }
        }
        #pragma unroll
        for (int nt = 0; nt < 8; ++nt) {
            float bb = sP[0][nt * 16 + l16];
            #pragma unroll
            for (int mt = 0; mt < 2; ++mt)
                #pragma unroll
                for (int r = 0; r < 4; ++r)
                    sB[wrow + mt * 16 + quad * 4 + r][nt * 16 + l16] = f2s(fmaxf(acc[mt][nt][r] + bb, 0.f));
        }
        #pragma unroll
        for (int mt = 0; mt < 2; ++mt)
            #pragma unroll
            for (int nt = 0; nt < 8; ++nt) acc[mt][nt] = (v4f){0.f, 0.f, 0.f, 0.f};
        #pragma unroll
        for (int kk = 0; kk < 4; ++kk) {
            v8s a0 = *(const v8s*)&sB[wrow + l16][kk * 32 + quad * 8];
            v8s a1 = *(const v8s*)&sB[wrow + 16 + l16][kk * 32 + quad * 8];
            #pragma unroll
            for (int nt = 0; nt < 8; ++nt) {
                v8s b = *(const v8s*)(W2t + (nt * 16 + l16) * 128 + kk * 32 + quad * 8);
                acc[0][nt] = MFMA(a0, b, acc[0][nt]);
                acc[1][nt] = MFMA(a1, b, acc[1][nt]);
            }
        }
        #pragma unroll
        for (int mt = 0; mt < 2; ++mt)
            #pragma unroll
            for (int r = 0; r < 4; ++r) {
                float s = 0.f, qq = 0.f;
                #pragma unroll
                for (int nt = 0; nt < 8; ++nt) {
                    float u = acc[mt][nt][r] + sP[1][nt * 16 + l16];
                    acc[mt][nt][r] = u;
                    s += u; qq += u * u;
                }
                #pragma unroll
                for (int d = 1; d < 16; d <<= 1) {
                    s += __shfl_xor(s, d);
                    qq += __shfl_xor(qq, d);
                }
                float mn = s * (1.f / 128.f);
                float rs = rsqrtf(qq * (1.f / 128.f) - mn * mn + 1e-5f);
                #pragma unroll
                for (int nt = 0; nt < 8; ++nt) {
                    const int n = nt * 16 + l16;
                    macc[mt][nt][r] += fmaxf((acc[mt][nt][r] - mn) * rs * sP[2][n] + sP[3][n], 0.f);
                }
            }
        __syncthreads();
    }
    const int nn = num_node[g];
    #pragma unroll
    for (int mt = 0; mt < 2; ++mt)
        #pragma unroll
        for (int nt = 0; nt < 8; ++nt)
            #pragma unroll
            for (int r = 0; r < 4; ++r) {
                const int i = wrow + mt * 16 + quad * 4 + r;
                const int n = nt * 16 + l16;
                float v = (i >= nn) ? 0.f : macc[mt][nt][r] * (1.f / 6.f);
                zm[((size_t)(b_s * 128 + i)) * 128 + n] = __float2bfloat16(v);
            }
}

// ---------------- fused gl stage v2 (single-buffer, passing R17) ----------------
__global__ __launch_bounds__(256) void k_gl_fused(
    const bf16* __restrict__ zm, const float* __restrict__ hb,
    const bf16* __restrict__ adjb,
    const bf16* __restrict__ s1Wt, const float* __restrict__ s1_b,
    const bf16* __restrict__ WTgl,
    const float* __restrict__ glb1, const float* __restrict__ glb2,
    const float* __restrict__ glg, const float* __restrict__ glbn,
    float* __restrict__ hsum)
{
    __shared__ __align__(16) short sB[128][136];
    __shared__ float sP[9][128];
    const int t = threadIdx.x;
    const int b_s = blockIdx.x;
    const int g = b_s >> 4;
    const int wave = t >> 6, lane = t & 63, quad = lane >> 4, l16 = lane & 15;
    const int wrow = wave << 5;

    for (int u = t; u < 9 * 128; u += 256) {
        const int a = u >> 7, n = u & 127;
        const float* src =
            (a == 0) ? glb1 : (a == 1) ? glb2 : (a == 2) ? glg : (a == 3) ? glbn :
            (a == 4) ? glb1 + 128 : (a == 5) ? glb2 + 128 : (a == 6) ? glg + 128 :
            (a == 7) ? glbn + 128 : s1_b;
        sP[a][n] = src[n];
    }

    v8s aA[2][4];
    {
        const bf16* ar = adjb + (size_t)g * 16384;
        #pragma unroll
        for (int mt = 0; mt < 2; ++mt)
            #pragma unroll
            for (int kk = 0; kk < 4; ++kk)
                aA[mt][kk] = *(const v8s*)(ar + (size_t)(wrow + mt * 16 + l16) * 128 + kk * 32 + quad * 8);
    }

    v4f acc[2][8];
    #pragma unroll
    for (int mt = 0; mt < 2; ++mt)
        #pragma unroll
        for (int nt = 0; nt < 8; ++nt) acc[mt][nt] = (v4f){0.f, 0.f, 0.f, 0.f};
    #pragma unroll
    for (int kk = 0; kk < 4; ++kk) {
        v8s a0 = *(const v8s*)(zm + ((size_t)(b_s * 128) + wrow + l16) * 128 + kk * 32 + quad * 8);
        v8s a1 = *(const v8s*)(zm + ((size_t)(b_s * 128) + wrow + 16 + l16) * 128 + kk * 32 + quad * 8);
        #pragma unroll
        for (int nt = 0; nt < 8; ++nt) {
            v8s b = *(const v8s*)(s1Wt + (nt * 16 + l16) * 128 + kk * 32 + quad * 8);
            acc[0][nt] = MFMA(a0, b, acc[0][nt]);
            acc[1][nt] = MFMA(a1, b, acc[1][nt]);
        }
    }
    __syncthreads();
    float hs_reg[2][8][4];
    #pragma unroll
    for (int mt = 0; mt < 2; ++mt)
        #pragma unroll
        for (int nt = 0; nt < 8; ++nt)
            #pragma unroll
            for (int r = 0; r < 4; ++r) {
                const int i = wrow + mt * 16 + quad * 4 + r;
                const int n = nt * 16 + l16;
                float v = fmaxf(acc[mt][nt][r] + sP[8][n], 0.f);
                v += hb[((size_t)(g * 128 + i)) * 128 + n];
                hs_reg[mt][nt][r] = v;
                sB[n][i] = f2s(v);
            }
    __syncthreads();

    for (int l = 0; l < 2; ++l) {
        const bf16* W1t = WTgl + (size_t)(2 * l) * 16384;
        const bf16* W2t = WTgl + (size_t)(2 * l + 1) * 16384;
        #pragma unroll
        for (int mt = 0; mt < 2; ++mt)
            #pragma unroll
            for (int nt = 0; nt < 8; ++nt) acc[mt][nt] = (v4f){0.f, 0.f, 0.f, 0.f};
        #pragma unroll
        for (int kk = 0; kk < 4; ++kk)
            #pragma unroll
            for (int nt = 0; nt < 8; ++nt) {
                v8s b = *(const v8s*)&sB[nt * 16 + l16][kk * 32 + quad * 8];
                acc[0][nt] = MFMA(aA[0][kk], b, acc[0][nt]);
                acc[1][nt] = MFMA(aA[1][kk], b, acc[1][nt]);
            }
        __syncthreads();
        #pragma unroll
        for (int nt = 0; nt < 8; ++nt)
            #pragma unroll
            for (int mt = 0; mt < 2; ++mt)
                #pragma unroll
                for (int r = 0; r < 4; ++r)
                    sB[wrow + mt * 16 + quad * 4 + r][nt * 16 + l16] = f2s(acc[mt][nt][r]);
        #pragma unroll
        for (int mt = 0; mt < 2; ++mt)
            #pragma unroll
            for (int nt = 0; nt < 8; ++nt) acc[mt][nt] = (v4f){0.f, 0.f, 0.f, 0.f};
        #pragma unroll
        for (int kk = 0; kk < 4; ++kk) {
            v8s a0 = *(const v8s*)&sB[wrow + l16][kk * 32 + quad * 8];
            v8s a1 = *(const v8s*)&sB[wrow + 16 + l16][kk * 32 + quad * 8];
            #pragma unroll
            for (int nt = 0; nt < 8; ++nt) {
                v8s b = *(const v8s*)(W1t + (nt * 16 + l16) * 128 + kk * 32 + quad * 8);
                acc[0][nt] = MFMA(a0, b, acc[0][nt]);
                acc[1][nt] = MFMA(a1, b, acc[1][nt]);
            }
        }
        #pragma unroll
        for (int nt = 0; nt < 8; ++nt) {
            float bb = sP[4 * l + 0][nt * 16 + l16];
            #pragma unroll
            for (int mt = 0; mt < 2; ++mt)
                #pragma unroll
                for (int r = 0; r < 4; ++r)
                    sB[wrow + mt * 16 + quad * 4 + r][nt * 16 + l16] = f2s(fmaxf(acc[mt][nt][r] + bb, 0.f));
        }
        #pragma unroll
        for (int mt = 0; mt < 2; ++mt)
            #pragma unroll
            for (int nt = 0; nt < 8; ++nt) acc[mt][nt] = (v4f){0.f, 0.f, 0.f, 0.f};
        #pragma unroll
        for (int kk = 0; kk < 4; ++kk) {
            v8s a0 = *(const v8s*)&sB[wrow + l16][kk * 32 + quad * 8];
            v8s a1 = *(const v8s*)&sB[wrow + 16 + l16][kk * 32 + quad * 8];
            #pragma unroll
            for (int nt = 0; nt < 8; ++nt) {
                v8s b = *(const v8s*)(W2t + (nt * 16 + l16) * 128 + kk * 32 + quad * 8);
                acc[0][nt] = MFMA(a0, b, acc[0][nt]);
                acc[1][nt] = MFMA(a1, b, acc[1][nt]);
            }
        }
        __syncthreads();
        #pragma unroll
        for (int mt = 0; mt < 2; ++mt)
            #pragma unroll
            for (int r = 0; r < 4; ++r) {
                float s = 0.f, qq = 0.f;
                #pragma unroll
                for (int nt = 0; nt < 8; ++nt) {
                    float u = acc[mt][nt][r] + sP[4 * l + 1][nt * 16 + l16];
                    acc[mt][nt][r] = u;
                    s += u; qq += u * u;
                }
                #pragma unroll
                for (int d = 1; d < 16; d <<= 1) {
                    s += __shfl_xor(s, d);
                    qq += __shfl_xor(qq, d);
                }
                float mn = s * (1.f / 128.f);
                float rs = rsqrtf(qq * (1.f / 128.f) - mn * mn + 1e-5f);
                const int i = wrow + mt * 16 + quad * 4 + r;
                #pragma unroll
                for (int nt = 0; nt < 8; ++nt) {
                    const int n = nt * 16 + l16;
                    float v = fmaxf((acc[mt][nt][r] - mn) * rs * sP[4 * l + 2][n] + sP[4 * l + 3][n], 0.f);
                    float h2 = hs_reg[mt][nt][r] + v;
                    hs_reg[mt][nt][r] = h2;
                    sB[n][i] = f2s(h2);
                }
            }
        __syncthreads();
    }

    float* sRedf = (float*)&sB[0][0];
    #pragma unroll
    for (int nt = 0; nt < 8; ++nt) {
        float part = 0.f;
        #pragma unroll
        for (int mt = 0; mt < 2; ++mt)
            #pragma unroll
            for (int r = 0; r < 4; ++r) part += hs_reg[mt][nt][r];
        sRedf[(wave * 4 + quad) * 128 + nt * 16 + l16] = part;
    }
    __syncthreads();
    if (t < 128) {
        float s = 0.f;
        #pragma unroll
        for (int r = 0; r < 16; ++r) s += sRedf[r * 128 + t];
        hsum[(size_t)b_s * 128 + t] = s;
    }
}

// ---------------- fused tail (passing, R17) ----------------
__global__ __launch_bounds__(128) void k_tail(const float* __restrict__ hsum,
    const float* __restrict__ s2W, const float* __restrict__ s2b,
    const float* __restrict__ rW1, const float* __restrict__ rb1,
    const float* __restrict__ rW2, const float* __restrict__ rb2,
    const float* __restrict__ rg, const float* __restrict__ rbn,
    const float* __restrict__ outW, const float* __restrict__ outb,
    float* __restrict__ out)
{
    __shared__ float sA[16][136];
    __shared__ float sV[128];
    __shared__ float red[128];
    const int g = blockIdx.x, hd = threadIdx.x;
    #pragma unroll
    for (int r = 0; r < 16; ++r) sA[r][hd] = hsum[((size_t)(g * 16 + r)) * 128 + hd];
    __syncthreads();
    float acc[16];
    #pragma unroll
    for (int r = 0; r < 16; ++r) acc[r] = s2b[hd];
    for (int k = 0; k < 128; k += 4) {
        float w0 = s2W[(k+0)*128+hd], w1 = s2W[(k+1)*128+hd], w2 = s2W[(k+2)*128+hd], w3 = s2W[(k+3)*128+hd];
        #pragma unroll
        for (int r = 0; r < 16; ++r) {
            float4 a = *(const float4*)&sA[r][k];
            acc[r] = fmaf(a.x, w0, acc[r]); acc[r] = fmaf(a.y, w1, acc[r]);
            acc[r] = fmaf(a.z, w2, acc[r]); acc[r] = fmaf(a.w, w3, acc[r]);
        }
    }
    float pool = -INFINITY;
    #pragma unroll
    for (int r = 0; r < 16; ++r) pool = fmaxf(pool, fmaxf(acc[r], 0.f));
    sV[hd] = pool;
    __syncthreads();
    float t1 = rb1[hd];
    for (int k = 0; k < 128; ++k) t1 = fmaf(sV[k], rW1[k * 128 + hd], t1);
    t1 = fmaxf(t1, 0.f);
    red[hd] = t1;
    __syncthreads();
    float u = rb2[hd];
    for (int k = 0; k < 128; ++k) u = fmaf(red[k], rW2[k * 128 + hd], u);
    float* rs1 = (float*)&sA[0][0];
    float* rs2 = (float*)&sA[2][0];
    rs1[hd] = u; rs2[hd] = u * u;
    __syncthreads();
    for (int s = 64; s > 0; s >>= 1) {
        if (hd < s) { rs1[hd] += rs1[hd + s]; rs2[hd] += rs2[hd + s]; }
        __syncthreads();
    }
    float mn = rs1[0] * (1.f / 128.f);
    float var = rs2[0] * (1.f / 128.f) - mn * mn;
    float rstd = rsqrtf(var + 1e-5f);
    float p2 = fmaxf((u - mn) * rstd * rg[hd] + rbn[hd], 0.f) + sV[hd];
    __syncthreads();
    red[hd] = p2 * outW[hd];
    __syncthreads();
    for (int s = 64; s > 0; s >>= 1) {
        if (hd < s) red[hd] += red[hd + s];
        __syncthreads();
    }
    if (hd == 0) out[g] = red[0] + outb[0];
}

extern "C" void kernel_launch(void* const* d_in, const int* in_sizes, int n_in,
                              void* d_out, int out_size, void* d_ws, size_t ws_size,
                              hipStream_t stream)
{
    (void)in_sizes; (void)n_in; (void)out_size; (void)ws_size;
    const float* x     = (const float*)d_in[0];
    const float* adj   = (const float*)d_in[1];
    const float* idemb = (const float*)d_in[2];
    const float* in_W1 = (const float*)d_in[3];
    const float* in_b1 = (const float*)d_in[4];
    const float* in_W2 = (const float*)d_in[5];
    const float* in_b2 = (const float*)d_in[6];
    const float* in_g  = (const float*)d_in[7];
    const float* in_bn = (const float*)d_in[8];
    const float* gW1   = (const float*)d_in[9];
    const float* gb1   = (const float*)d_in[10];
    const float* gW2   = (const float*)d_in[11];
    const float* gb2   = (const float*)d_in[12];
    const float* gg    = (const float*)d_in[13];
    const float* gbn   = (const float*)d_in[14];
    const float* iW1   = (const float*)d_in[15];
    const float* ib1   = (const float*)d_in[16];
    const float* iW2   = (const float*)d_in[17];
    const float* ib2   = (const float*)d_in[18];
    const float* ig    = (const float*)d_in[19];
    const float* ibn   = (const float*)d_in[20];
    const float* glW1  = (const float*)d_in[21];
    const float* glb1  = (const float*)d_in[22];
    const float* glW2  = (const float*)d_in[23];
    const float* glb2  = (const float*)d_in[24];
    const float* glg   = (const float*)d_in[25];
    const float* glbn  = (const float*)d_in[26];
    const float* s1_W  = (const float*)d_in[27];
    const float* s1_b  = (const float*)d_in[28];
    const float* s2_W  = (const float*)d_in[29];
    const float* s2_b  = (const float*)d_in[30];
    const float* rW1   = (const float*)d_in[31];
    const float* rb1   = (const float*)d_in[32];
    const float* rW2   = (const float*)d_in[33];
    const float* rb2   = (const float*)d_in[34];
    const float* rg    = (const float*)d_in[35];
    const float* rbn   = (const float*)d_in[36];
    const float* out_W = (const float*)d_in[37];
    const float* out_b = (const float*)d_in[38];
    const int* subgs   = (const int*)d_in[39];
    const int* num_node= (const int*)d_in[41];
    const int* allperm = (const int*)d_in[42];

    // ---- workspace layout (unchanged budget) ----
    const size_t MB_ = (size_t)512 * 128 * P_ * H_ * 2;        // 100,663,296: z2t
    char* w = (char*)d_ws;
    bf16*  mz     = (bf16*)(w);                                // region A: z2t
    bf16*  s1Wt   = (bf16*)(w + 33554432ull);                  // s1_W^T bf16 (written in prep; region A head is z2t which starts AFTER... careful)
    bf16*  zm     = (bf16*)(w + MB_);                          // (512,128,128) bf16 = 16.8 MB
    bf16*  WT     = (bf16*)(w + MB_ + 16777216ull);            // 8 x (128x128) bf16 transposed
    char*  wc     = w + MB_ + 16777216ull + 262144ull;
    float* hb     = (float*)(wc);                              // h (32,128,128) f32  2 MB
    bf16*  adjb   = (bf16*)(wc + 2097152ull);                  // 1 MB
    bf16*  WT2    = (bf16*)(wc + 3145728ull);                  // 8 x 32KB = 256 KB
    float* hsum   = (float*)(wc + 4194304ull);                 // (512,128)
    bf16*  s1WtX  = (bf16*)(wc + 4456448ull);                  // s1_W^T bf16 32KB (safe slot, outside z2t)
    float* degf   = (float*)(wc + 4964352ull);                 // 4096 f32
    float* outp   = (float*)d_out;
    (void)s1Wt;

    // prep: deg+adjb + WT x8 + WT2 x8 + s1Wt  (one dispatch)
    k_prep<<<6272, 128, 0, stream>>>(adj, degf, adjb,
        iW1, iW2, glW1, glW2, in_W2, gW1, gW2, s1_W,
        WT, WT2, s1WtX);

    // FAT: id1 (3072 blocks) + h-pipeline (32 blocks) in one dispatch
    k_id1h<<<3104, 256, 0, stream>>>(
        adj, degf, subgs, allperm, idemb, mz,
        WT, ib1, WT + 16384, ib2, ig, ibn,
        x, adjb, in_W1, in_b1,
        WT2, in_b2, in_g, in_bn,
        WT2 + 16384, gb1, gb2, gg, gbn, hb);

    // ID layer 2 v9 -> zm
    k_id2_v9<<<512, 256, 0, stream>>>(mz, zm, adjb, num_node, subgs, allperm, idemb,
        WT + 2 * 16384, ib1 + 128, WT + 3 * 16384, ib2 + 128, ig + 128, ibn + 128);

    // fused gl v2 (single-buffer): setmlp1 + 2 gl layers + node-sum -> hsum
    k_gl_fused<<<512, 256, 0, stream>>>(zm, hb, adjb, s1WtX, s1_b,
        WT + 4 * 16384, glb1, glb2, glg, glbn, hsum);

    // fused tail: setmlp2 + maxpool + setmlp3 + out proj
    k_tail<<<32, 128, 0, stream>>>(hsum, s2_W, s2_b, rW1, rb1, rW2, rb2,
        rg, rbn, out_W, out_b, outp);
}

// Round 19
// 550.141 us; speedup vs baseline: 1.1110x; 1.1110x over previous
//
#include <hip/hip_runtime.h>
#include <hip/hip_bf16.h>
#include <string.h>

typedef __hip_bfloat16 bf16;
typedef short v8s __attribute__((ext_vector_type(8)));
typedef float v4f __attribute__((ext_vector_type(4)));

#define H_ 128
#define P_ 6
#define K_ 4

__device__ __forceinline__ float s2f(short s) {
    unsigned int u = ((unsigned int)(unsigned short)s) << 16;
    float f; __builtin_memcpy(&f, &u, 4); return f;
}
__device__ __forceinline__ short f2s(float v) {
    bf16 h = __float2bfloat16(v);
    short s; __builtin_memcpy(&s, &h, 2); return s;
}
__device__ __forceinline__ v4f MFMA(v8s a, v8s b, v4f c) {
    return __builtin_amdgcn_mfma_f32_16x16x32_bf16(a, b, c, 0, 0, 0);
}

// ---------------- merged prep: deg+adjb (rows), WT x8, WT2 x8, s1Wt ----------------
__global__ __launch_bounds__(128) void k_prep(const float* __restrict__ adj,
    float* __restrict__ degf, bf16* __restrict__ adjb,
    const float* __restrict__ iW1, const float* __restrict__ iW2,
    const float* __restrict__ glW1, const float* __restrict__ glW2,
    const float* __restrict__ in_W2, const float* __restrict__ gW1,
    const float* __restrict__ gW2, const float* __restrict__ s1_W,
    bf16* __restrict__ WT, bf16* __restrict__ WT2, bf16* __restrict__ s1Wt)
{
    __shared__ float red[128];
    const int b = blockIdx.x, t = threadIdx.x;
    if (b < 4096) {
        float a = adj[(size_t)b * 128 + t];
        adjb[(size_t)b * 128 + t] = __float2bfloat16(a);
        red[t] = a;
        __syncthreads();
        for (int s = 64; s > 0; s >>= 1) {
            if (t < s) red[t] += red[t + s];
            __syncthreads();
        }
        if (t == 0) degf[b] = red[0];
    } else if (b < 5120) {
        const int bb = b - 4096, w = bb >> 7, n = bb & 127;
        const float* arr[8] = {iW1, iW2, iW1 + 16384, iW2 + 16384,
                               glW1, glW2, glW1 + 16384, glW2 + 16384};
        WT[(size_t)w * 16384 + n * 128 + t] = __float2bfloat16(arr[w][t * 128 + n]);
    } else if (b < 6144) {
        const int bb = b - 5120, w = bb >> 7, n = bb & 127;
        const float* arr[8] = {in_W2, gW1, gW2, gW1 + 16384,
                               gW2 + 16384, gW1 + 32768, gW2 + 32768, in_W2};
        WT2[(size_t)w * 16384 + n * 128 + t] = __float2bfloat16(arr[w][t * 128 + n]);
    } else {
        const int n = b - 6144;
        s1Wt[n * 128 + t] = __float2bfloat16(s1_W[t * 128 + n]);
    }
}

// ---------------- h-pipeline FUSED (dual-buffer, passing R16/R17) ----------------
__global__ __launch_bounds__(256) void k_h_fused(
    const float* __restrict__ x, const bf16* __restrict__ adjb,
    const float* __restrict__ inW1, const float* __restrict__ inb1,
    const bf16* __restrict__ inW2t, const float* __restrict__ inb2,
    const float* __restrict__ ing, const float* __restrict__ inbn,
    const bf16* __restrict__ WTg,
    const float* __restrict__ gb1, const float* __restrict__ gb2,
    const float* __restrict__ gg, const float* __restrict__ gbn,
    float* __restrict__ hb)
{
    __shared__ __align__(16) short sHsT[128][136];
    __shared__ __align__(16) short sM[128][136];
    __shared__ float sP[15][128];
    const int t = threadIdx.x;
    const int g = blockIdx.x;
    const int wave = t >> 6, lane = t & 63, quad = lane >> 4, l16 = lane & 15;
    const int wrow = wave << 5;

    for (int u = t; u < 15 * 128; u += 256) {
        const int a = u >> 7, n = u & 127;
        const float* src;
        if (a == 0) src = inb2;
        else if (a == 1) src = ing;
        else if (a == 2) src = inbn;
        else {
            const int l = (a - 3) >> 2, pp = (a - 3) & 3;
            src = (pp == 0) ? gb1 + l * 128 : (pp == 1) ? gb2 + l * 128
                : (pp == 2) ? gg + l * 128 : gbn + l * 128;
        }
        sP[a][n] = src[n];
    }

    v8s aA[2][4];
    {
        const bf16* ar = adjb + (size_t)g * 16384;
        #pragma unroll
        for (int mt = 0; mt < 2; ++mt)
            #pragma unroll
            for (int kk = 0; kk < 4; ++kk)
                aA[mt][kk] = *(const v8s*)(ar + (size_t)(wrow + mt * 16 + l16) * 128 + kk * 32 + quad * 8);
    }

    {
        const int i = t >> 1, half = (t & 1) * 64;
        const float xv = x[(size_t)g * 128 + i];
        #pragma unroll
        for (int fb = 0; fb < 64; fb += 8) {
            v8s pk;
            #pragma unroll
            for (int e = 0; e < 8; ++e)
                pk[e] = f2s(fmaxf(fmaf(xv, inW1[half + fb + e], inb1[half + fb + e]), 0.f));
            *(v8s*)&sM[i][half + fb] = pk;
        }
    }
    __syncthreads();

    v4f acc[2][8];
    #pragma unroll
    for (int mt = 0; mt < 2; ++mt)
        #pragma unroll
        for (int nt = 0; nt < 8; ++nt) acc[mt][nt] = (v4f){0.f, 0.f, 0.f, 0.f};
    #pragma unroll
    for (int kk = 0; kk < 4; ++kk) {
        v8s a0 = *(const v8s*)&sM[wrow + l16][kk * 32 + quad * 8];
        v8s a1 = *(const v8s*)&sM[wrow + 16 + l16][kk * 32 + quad * 8];
        #pragma unroll
        for (int nt = 0; nt < 8; ++nt) {
            v8s b = *(const v8s*)(inW2t + (nt * 16 + l16) * 128 + kk * 32 + quad * 8);
            acc[0][nt] = MFMA(a0, b, acc[0][nt]);
            acc[1][nt] = MFMA(a1, b, acc[1][nt]);
        }
    }
    float hs_reg[2][8][4];
    #pragma unroll
    for (int mt = 0; mt < 2; ++mt)
        #pragma unroll
        for (int r = 0; r < 4; ++r) {
            float s = 0.f, qq = 0.f;
            #pragma unroll
            for (int nt = 0; nt < 8; ++nt) {
                float u = acc[mt][nt][r] + sP[0][nt * 16 + l16];
                acc[mt][nt][r] = u;
                s += u; qq += u * u;
            }
            #pragma unroll
            for (int d = 1; d < 16; d <<= 1) {
                s += __shfl_xor(s, d);
                qq += __shfl_xor(qq, d);
            }
            float mn = s * (1.f / 128.f);
            float rs = rsqrtf(qq * (1.f / 128.f) - mn * mn + 1e-5f);
            const int i = wrow + mt * 16 + quad * 4 + r;
            #pragma unroll
            for (int nt = 0; nt < 8; ++nt) {
                const int n = nt * 16 + l16;
                float v = fmaxf((acc[mt][nt][r] - mn) * rs * sP[1][n] + sP[2][n], 0.f);
                hs_reg[mt][nt][r] = v;
                sHsT[n][i] = f2s(v);
            }
        }
    __syncthreads();

    for (int l = 0; l < 3; ++l) {
        const bf16* W1t = WTg + (size_t)(2 * l) * 16384;
        const bf16* W2t = WTg + (size_t)(2 * l + 1) * 16384;
        #pragma unroll
        for (int mt = 0; mt < 2; ++mt)
            #pragma unroll
            for (int nt = 0; nt < 8; ++nt) acc[mt][nt] = (v4f){0.f, 0.f, 0.f, 0.f};
        #pragma unroll
        for (int kk = 0; kk < 4; ++kk)
            #pragma unroll
            for (int nt = 0; nt < 8; ++nt) {
                v8s b = *(const v8s*)&sHsT[nt * 16 + l16][kk * 32 + quad * 8];
                acc[0][nt] = MFMA(aA[0][kk], b, acc[0][nt]);
                acc[1][nt] = MFMA(aA[1][kk], b, acc[1][nt]);
            }
        #pragma unroll
        for (int nt = 0; nt < 8; ++nt)
            #pragma unroll
            for (int mt = 0; mt < 2; ++mt)
                #pragma unroll
                for (int r = 0; r < 4; ++r)
                    sM[wrow + mt * 16 + quad * 4 + r][nt * 16 + l16] = f2s(acc[mt][nt][r]);
        __syncthreads();
        #pragma unroll
        for (int mt = 0; mt < 2; ++mt)
            #pragma unroll
            for (int nt = 0; nt < 8; ++nt) acc[mt][nt] = (v4f){0.f, 0.f, 0.f, 0.f};
        #pragma unroll
        for (int kk = 0; kk < 4; ++kk) {
            v8s a0 = *(const v8s*)&sM[wrow + l16][kk * 32 + quad * 8];
            v8s a1 = *(const v8s*)&sM[wrow + 16 + l16][kk * 32 + quad * 8];
            #pragma unroll
            for (int nt = 0; nt < 8; ++nt) {
                v8s b = *(const v8s*)(W1t + (nt * 16 + l16) * 128 + kk * 32 + quad * 8);
                acc[0][nt] = MFMA(a0, b, acc[0][nt]);
                acc[1][nt] = MFMA(a1, b, acc[1][nt]);
            }
        }
        #pragma unroll
        for (int nt = 0; nt < 8; ++nt) {
            float bb = sP[3 + 4 * l + 0][nt * 16 + l16];
            #pragma unroll
            for (int mt = 0; mt < 2; ++mt)
                #pragma unroll
                for (int r = 0; r < 4; ++r)
                    sM[wrow + mt * 16 + quad * 4 + r][nt * 16 + l16] = f2s(fmaxf(acc[mt][nt][r] + bb, 0.f));
        }
        #pragma unroll
        for (int mt = 0; mt < 2; ++mt)
            #pragma unroll
            for (int nt = 0; nt < 8; ++nt) acc[mt][nt] = (v4f){0.f, 0.f, 0.f, 0.f};
        #pragma unroll
        for (int kk = 0; kk < 4; ++kk) {
            v8s a0 = *(const v8s*)&sM[wrow + l16][kk * 32 + quad * 8];
            v8s a1 = *(const v8s*)&sM[wrow + 16 + l16][kk * 32 + quad * 8];
            #pragma unroll
            for (int nt = 0; nt < 8; ++nt) {
                v8s b = *(const v8s*)(W2t + (nt * 16 + l16) * 128 + kk * 32 + quad * 8);
                acc[0][nt] = MFMA(a0, b, acc[0][nt]);
                acc[1][nt] = MFMA(a1, b, acc[1][nt]);
            }
        }
        #pragma unroll
        for (int mt = 0; mt < 2; ++mt)
            #pragma unroll
            for (int r = 0; r < 4; ++r) {
                float s = 0.f, qq = 0.f;
                #pragma unroll
                for (int nt = 0; nt < 8; ++nt) {
                    float u = acc[mt][nt][r] + sP[3 + 4 * l + 1][nt * 16 + l16];
                    acc[mt][nt][r] = u;
                    s += u; qq += u * u;
                }
                #pragma unroll
                for (int d = 1; d < 16; d <<= 1) {
                    s += __shfl_xor(s, d);
                    qq += __shfl_xor(qq, d);
                }
                float mn = s * (1.f / 128.f);
                float rs = rsqrtf(qq * (1.f / 128.f) - mn * mn + 1e-5f);
                const int i = wrow + mt * 16 + quad * 4 + r;
                #pragma unroll
                for (int nt = 0; nt < 8; ++nt) {
                    const int n = nt * 16 + l16;
                    float v = fmaxf((acc[mt][nt][r] - mn) * rs * sP[3 + 4 * l + 2][n] + sP[3 + 4 * l + 3][n], 0.f);
                    float h2 = hs_reg[mt][nt][r] + v;
                    hs_reg[mt][nt][r] = h2;
                    sHsT[n][i] = f2s(h2);
                }
            }
        __syncthreads();
    }

    #pragma unroll
    for (int mt = 0; mt < 2; ++mt)
        #pragma unroll
        for (int nt = 0; nt < 8; ++nt)
            #pragma unroll
            for (int r = 0; r < 4; ++r) {
                const int i = wrow + mt * 16 + quad * 4 + r;
                const int n = nt * 16 + l16;
                hb[((size_t)(g * 128 + i)) * 128 + n] = hs_reg[mt][nt][r];
            }
}

// ---------------- ID layer 1 FUSED (single-buffer, 92 VGPR, passing R15-R17) ----------------
__global__ __launch_bounds__(256) void k_id1_fused(
    const float* __restrict__ adj, const float* __restrict__ degf,
    const int* __restrict__ subgs, const int* __restrict__ allperm,
    const float* __restrict__ idemb, bf16* __restrict__ outb,
    const bf16* __restrict__ W1t, const float* __restrict__ b1,
    const bf16* __restrict__ W2t, const float* __restrict__ b2,
    const float* __restrict__ gam, const float* __restrict__ bet)
{
    __shared__ __align__(16) short sB[128][136];
    __shared__ float sE[K_][128];
    const int t = threadIdx.x;
    const int bi = blockIdx.x;
    const int b_s = bi / 6, p = bi - b_s * 6;
    const int g = b_s >> 4;
    const int wave = t >> 6, lane = t & 63;
    const int quad = lane >> 4, l16 = lane & 15;
    const int wrow = wave << 5;

    int nodeq[K_];
    #pragma unroll
    for (int q = 0; q < K_; ++q) nodeq[q] = subgs[b_s * K_ + q];

    for (int u = t; u < K_ * 128; u += 256) {
        const int q = u >> 7, f = u & 127;
        sE[q][f] = idemb[(size_t)allperm[q * P_ + p] * H_ + f] - 1.f;
    }
    __syncthreads();

    {
        const int i = t >> 1, half = (t & 1) * 64;
        const int gi = g * 128 + i;
        const float dg = degf[gi];
        float aq[K_];
        #pragma unroll
        for (int q = 0; q < K_; ++q) aq[q] = adj[(size_t)gi * 128 + nodeq[q]];
        #pragma unroll
        for (int f = 0; f < 64; ++f) {
            float v = dg;
            #pragma unroll
            for (int q = 0; q < K_; ++q) v = fmaf(aq[q], sE[q][half + f], v);
            sB[i][half + f] = f2s(v);
        }
    }
    __syncthreads();

    v4f acc[2][8];
    #pragma unroll
    for (int mt = 0; mt < 2; ++mt)
        #pragma unroll
        for (int nt = 0; nt < 8; ++nt) acc[mt][nt] = (v4f){0.f, 0.f, 0.f, 0.f};
    #pragma unroll
    for (int kk = 0; kk < 4; ++kk) {
        v8s a0 = *(const v8s*)&sB[wrow + l16][kk * 32 + quad * 8];
        v8s a1 = *(const v8s*)&sB[wrow + 16 + l16][kk * 32 + quad * 8];
        #pragma unroll
        for (int nt = 0; nt < 8; ++nt) {
            v8s b = *(const v8s*)(W1t + (nt * 16 + l16) * 128 + kk * 32 + quad * 8);
            acc[0][nt] = MFMA(a0, b, acc[0][nt]);
            acc[1][nt] = MFMA(a1, b, acc[1][nt]);
        }
    }
    #pragma unroll
    for (int nt = 0; nt < 8; ++nt) {
        float bb = b1[nt * 16 + l16];
        #pragma unroll
        for (int mt = 0; mt < 2; ++mt)
            #pragma unroll
            for (int r = 0; r < 4; ++r)
                sB[wrow + mt * 16 + quad * 4 + r][nt * 16 + l16] = f2s(fmaxf(acc[mt][nt][r] + bb, 0.f));
    }
    #pragma unroll
    for (int mt = 0; mt < 2; ++mt)
        #pragma unroll
        for (int nt = 0; nt < 8; ++nt) acc[mt][nt] = (v4f){0.f, 0.f, 0.f, 0.f};
    #pragma unroll
    for (int kk = 0; kk < 4; ++kk) {
        v8s a0 = *(const v8s*)&sB[wrow + l16][kk * 32 + quad * 8];
        v8s a1 = *(const v8s*)&sB[wrow + 16 + l16][kk * 32 + quad * 8];
        #pragma unroll
        for (int nt = 0; nt < 8; ++nt) {
            v8s b = *(const v8s*)(W2t + (nt * 16 + l16) * 128 + kk * 32 + quad * 8);
            acc[0][nt] = MFMA(a0, b, acc[0][nt]);
            acc[1][nt] = MFMA(a1, b, acc[1][nt]);
        }
    }
    float bb2[8], gv[8], bv[8];
    #pragma unroll
    for (int nt = 0; nt < 8; ++nt) {
        int n = nt * 16 + l16;
        bb2[nt] = b2[n]; gv[nt] = gam[n]; bv[nt] = bet[n];
    }
    #pragma unroll
    for (int mt = 0; mt < 2; ++mt)
        #pragma unroll
        for (int r = 0; r < 4; ++r) {
            float s = 0.f, q = 0.f;
            #pragma unroll
            for (int nt = 0; nt < 8; ++nt) {
                float u = acc[mt][nt][r] + bb2[nt];
                acc[mt][nt][r] = u;
                s += u; q += u * u;
            }
            #pragma unroll
            for (int d = 1; d < 16; d <<= 1) {
                s += __shfl_xor(s, d);
                q += __shfl_xor(q, d);
            }
            float mn = s * (1.f / 128.f);
            float rs = rsqrtf(q * (1.f / 128.f) - mn * mn + 1e-5f);
            #pragma unroll
            for (int nt = 0; nt < 8; ++nt) {
                float v = fmaxf((acc[mt][nt][r] - mn) * rs * gv[nt] + bv[nt], 0.f);
                sB[wrow + mt * 16 + quad * 4 + r][nt * 16 + l16] = f2s(v + 1.0f);
            }
        }
    __syncthreads();
    {
        const int f = t >> 1, nh = (t & 1) * 64;
        const short* flat = &sB[0][0];
        bf16* dst = outb + (size_t)bi * 16384 + (size_t)f * 128 + nh;
        #pragma unroll
        for (int u = 0; u < 8; ++u) {
            v8s pk;
            #pragma unroll
            for (int e = 0; e < 8; ++e) pk[e] = flat[(nh + u * 8 + e) * 136 + f];
            *(v8s*)(dst + u * 8) = pk;
        }
    }
}

// ---------------- ID layer 2 v9 (passing, R13) ----------------
__global__ __launch_bounds__(256) void k_id2_v9(
    const bf16* __restrict__ z2t, bf16* __restrict__ zm,
    const bf16* __restrict__ adjb, const int* __restrict__ num_node,
    const int* __restrict__ subgs, const int* __restrict__ allperm,
    const float* __restrict__ idemb,
    const bf16* __restrict__ W1t, const float* __restrict__ b1,
    const bf16* __restrict__ W2t, const float* __restrict__ b2,
    const float* __restrict__ gam, const float* __restrict__ bet)
{
    __shared__ __align__(16) short sB[128][136];
    __shared__ float sP[4][128];
    const int t = threadIdx.x;
    const int b_s = blockIdx.x;
    const int g = b_s >> 4;
    const int wave = t >> 6, lane = t & 63, quad = lane >> 4, l16 = lane & 15;
    const int wrow = wave << 5;

    #pragma unroll
    for (int u = 0; u < 2; ++u) {
        const int v = t + u * 256;
        const int a = v >> 7, n = v & 127;
        const float* src = (a == 0) ? b1 : (a == 1) ? b2 : (a == 2) ? gam : bet;
        sP[a][n] = src[n];
    }

    v8s aA[2][4];
    {
        const bf16* ar = adjb + (size_t)g * 16384;
        #pragma unroll
        for (int mt = 0; mt < 2; ++mt)
            #pragma unroll
            for (int kk = 0; kk < 4; ++kk)
                aA[mt][kk] = *(const v8s*)(ar + (size_t)(wrow + mt * 16 + l16) * 128 + kk * 32 + quad * 8);
    }
    int nodeq[K_];
    #pragma unroll
    for (int q = 0; q < K_; ++q) nodeq[q] = subgs[b_s * K_ + q];

    float macc[2][8][4];
    #pragma unroll
    for (int mt = 0; mt < 2; ++mt)
        #pragma unroll
        for (int nt = 0; nt < 8; ++nt)
            #pragma unroll
            for (int r = 0; r < 4; ++r) macc[mt][nt][r] = 0.f;

    const int sf = t >> 1, shalf = (t & 1) * 64;

    for (int p = 0; p < P_; ++p) {
        {
            const bf16* src = z2t + ((size_t)(b_s * P_ + p)) * 16384 + (size_t)sf * 128 + shalf;
            #pragma unroll
            for (int u = 0; u < 8; ++u)
                *(v8s*)&sB[sf][shalf + u * 8] = *(const v8s*)(src + u * 8);
        }
        __syncthreads();
        if (t < 128) {
            #pragma unroll
            for (int q = 0; q < K_; ++q) {
                float e = idemb[(size_t)allperm[q * P_ + p] * H_ + t] - 1.f;
                short* cell = &sB[t][nodeq[q]];
                *cell = f2s(s2f(*cell) + e);
            }
        }
        __syncthreads();
        #pragma unroll
        for (int mt = 0; mt < 2; ++mt)
            #pragma unroll
            for (int nt = 0; nt < 8; ++nt) {
                const int n = nt * 16 + l16;
                #pragma unroll
                for (int r = 0; r < 4; ++r)
                    macc[mt][nt][r] += s2f(sB[n][wrow + mt * 16 + quad * 4 + r]);
            }
        v4f acc[2][8];
        #pragma unroll
        for (int mt = 0; mt < 2; ++mt)
            #pragma unroll
            for (int nt = 0; nt < 8; ++nt) acc[mt][nt] = (v4f){0.f, 0.f, 0.f, 0.f};
        #pragma unroll
        for (int kk = 0; kk < 4; ++kk)
            #pragma unroll
            for (int nt = 0; nt < 8; ++nt) {
                v8s b = *(const v8s*)&sB[nt * 16 + l16][kk * 32 + quad * 8];
                acc[0][nt] = MFMA(aA[0][kk], b, acc[0][nt]);
                acc[1][nt] = MFMA(aA[1][kk], b, acc[1][nt]);
            }
        __syncthreads();
        #pragma unroll
        for (int nt = 0; nt < 8; ++nt)
            #pragma unroll
            for (int mt = 0; mt < 2; ++mt)
                #pragma unroll
                for (int r = 0; r < 4; ++r)
                    sB[wrow + mt * 16 + quad * 4 + r][nt * 16 + l16] = f2s(acc[mt][nt][r]);
        #pragma unroll
        for (int mt = 0; mt < 2; ++mt)
            #pragma unroll
            for (int nt = 0; nt < 8; ++nt) acc[mt][nt] = (v4f){0.f, 0.f, 0.f, 0.f};
        #pragma unroll
        for (int kk = 0; kk < 4; ++kk) {
            v8s a0 = *(const v8s*)&sB[wrow + l16][kk * 32 + quad * 8];
            v8s a1 = *(const v8s*)&sB[wrow + 16 + l16][kk * 32 + quad * 8];
            #pragma unroll
            for (int nt = 0; nt < 8; ++nt) {
                v8s b = *(const v8s*)(W1t + (nt * 16 + l16) * 128 + kk * 32 + quad * 8);
                acc[0][nt] = MFMA(a0, b, acc[0][nt]);
                acc[1][nt] = MFMA(a1, b, acc[1][nt]);
            }
        }
        #pragma unroll
        for (int nt = 0; nt < 8; ++nt) {
            float bb = sP[0][nt * 16 + l16];
            #pragma unroll
            for (int mt = 0; mt < 2; ++mt)
                #pragma unroll
                for (int r = 0; r < 4; ++r)
                    sB[wrow + mt * 16 + quad * 4 + r][nt * 16 + l16] = f2s(fmaxf(acc[mt][nt][r] + bb, 0.f));
        }
        #pragma unroll
        for (int mt = 0; mt < 2; ++mt)
            #pragma unroll
            for (int nt = 0; nt < 8; ++nt) acc[mt][nt] = (v4f){0.f, 0.f, 0.f, 0.f};
        #pragma unroll
        for (int kk = 0; kk < 4; ++kk) {
            v8s a0 = *(const v8s*)&sB[wrow + l16][kk * 32 + quad * 8];
            v8s a1 = *(const v8s*)&sB[wrow + 16 + l16][kk * 32 + quad * 8];
            #pragma unroll
            for (int nt = 0; nt < 8; ++nt) {
                v8s b = *(const v8s*)(W2t + (nt * 16 + l16) * 128 + kk * 32 + quad * 8);
                acc[0][nt] = MFMA(a0, b, acc[0][nt]);
                acc[1][nt] = MFMA(a1, b, acc[1][nt]);
            }
        }
        #pragma unroll
        for (int mt = 0; mt < 2; ++mt)
            #pragma unroll
            for (int r = 0; r < 4; ++r) {
                float s = 0.f, qq = 0.f;
                #pragma unroll
                for (int nt = 0; nt < 8; ++nt) {
                    float u = acc[mt][nt][r] + sP[1][nt * 16 + l16];
                    acc[mt][nt][r] = u;
                    s += u; qq += u * u;
                }
                #pragma unroll
                for (int d = 1; d < 16; d <<= 1) {
                    s += __shfl_xor(s, d);
                    qq += __shfl_xor(qq, d);
                }
                float mn = s * (1.f / 128.f);
                float rs = rsqrtf(qq * (1.f / 128.f) - mn * mn + 1e-5f);
                #pragma unroll
                for (int nt = 0; nt < 8; ++nt) {
                    const int n = nt * 16 + l16;
                    macc[mt][nt][r] += fmaxf((acc[mt][nt][r] - mn) * rs * sP[2][n] + sP[3][n], 0.f);
                }
            }
        __syncthreads();
    }
    const int nn = num_node[g];
    #pragma unroll
    for (int mt = 0; mt < 2; ++mt)
        #pragma unroll
        for (int nt = 0; nt < 8; ++nt)
            #pragma unroll
            for (int r = 0; r < 4; ++r) {
                const int i = wrow + mt * 16 + quad * 4 + r;
                const int n = nt * 16 + l16;
                float v = (i >= nn) ? 0.f : macc[mt][nt][r] * (1.f / 6.f);
                zm[((size_t)(b_s * 128 + i)) * 128 + n] = __float2bfloat16(v);
            }
}

// ---------------- fused gl stage v2 (single-buffer, passing R17) ----------------
__global__ __launch_bounds__(256) void k_gl_fused(
    const bf16* __restrict__ zm, const float* __restrict__ hb,
    const bf16* __restrict__ adjb,
    const bf16* __restrict__ s1Wt, const float* __restrict__ s1_b,
    const bf16* __restrict__ WTgl,
    const float* __restrict__ glb1, const float* __restrict__ glb2,
    const float* __restrict__ glg, const float* __restrict__ glbn,
    float* __restrict__ hsum)
{
    __shared__ __align__(16) short sB[128][136];
    __shared__ float sP[9][128];
    const int t = threadIdx.x;
    const int b_s = blockIdx.x;
    const int g = b_s >> 4;
    const int wave = t >> 6, lane = t & 63, quad = lane >> 4, l16 = lane & 15;
    const int wrow = wave << 5;

    for (int u = t; u < 9 * 128; u += 256) {
        const int a = u >> 7, n = u & 127;
        const float* src =
            (a == 0) ? glb1 : (a == 1) ? glb2 : (a == 2) ? glg : (a == 3) ? glbn :
            (a == 4) ? glb1 + 128 : (a == 5) ? glb2 + 128 : (a == 6) ? glg + 128 :
            (a == 7) ? glbn + 128 : s1_b;
        sP[a][n] = src[n];
    }

    v8s aA[2][4];
    {
        const bf16* ar = adjb + (size_t)g * 16384;
        #pragma unroll
        for (int mt = 0; mt < 2; ++mt)
            #pragma unroll
            for (int kk = 0; kk < 4; ++kk)
                aA[mt][kk] = *(const v8s*)(ar + (size_t)(wrow + mt * 16 + l16) * 128 + kk * 32 + quad * 8);
    }

    v4f acc[2][8];
    #pragma unroll
    for (int mt = 0; mt < 2; ++mt)
        #pragma unroll
        for (int nt = 0; nt < 8; ++nt) acc[mt][nt] = (v4f){0.f, 0.f, 0.f, 0.f};
    #pragma unroll
    for (int kk = 0; kk < 4; ++kk) {
        v8s a0 = *(const v8s*)(zm + ((size_t)(b_s * 128) + wrow + l16) * 128 + kk * 32 + quad * 8);
        v8s a1 = *(const v8s*)(zm + ((size_t)(b_s * 128) + wrow + 16 + l16) * 128 + kk * 32 + quad * 8);
        #pragma unroll
        for (int nt = 0; nt < 8; ++nt) {
            v8s b = *(const v8s*)(s1Wt + (nt * 16 + l16) * 128 + kk * 32 + quad * 8);
            acc[0][nt] = MFMA(a0, b, acc[0][nt]);
            acc[1][nt] = MFMA(a1, b, acc[1][nt]);
        }
    }
    __syncthreads();
    float hs_reg[2][8][4];
    #pragma unroll
    for (int mt = 0; mt < 2; ++mt)
        #pragma unroll
        for (int nt = 0; nt < 8; ++nt)
            #pragma unroll
            for (int r = 0; r < 4; ++r) {
                const int i = wrow + mt * 16 + quad * 4 + r;
                const int n = nt * 16 + l16;
                float v = fmaxf(acc[mt][nt][r] + sP[8][n], 0.f);
                v += hb[((size_t)(g * 128 + i)) * 128 + n];
                hs_reg[mt][nt][r] = v;
                sB[n][i] = f2s(v);
            }
    __syncthreads();

    for (int l = 0; l < 2; ++l) {
        const bf16* W1t = WTgl + (size_t)(2 * l) * 16384;
        const bf16* W2t = WTgl + (size_t)(2 * l + 1) * 16384;
        #pragma unroll
        for (int mt = 0; mt < 2; ++mt)
            #pragma unroll
            for (int nt = 0; nt < 8; ++nt) acc[mt][nt] = (v4f){0.f, 0.f, 0.f, 0.f};
        #pragma unroll
        for (int kk = 0; kk < 4; ++kk)
            #pragma unroll
            for (int nt = 0; nt < 8; ++nt) {
                v8s b = *(const v8s*)&sB[nt * 16 + l16][kk * 32 + quad * 8];
                acc[0][nt] = MFMA(aA[0][kk], b, acc[0][nt]);
                acc[1][nt] = MFMA(aA[1][kk], b, acc[1][nt]);
            }
        __syncthreads();
        #pragma unroll
        for (int nt = 0; nt < 8; ++nt)
            #pragma unroll
            for (int mt = 0; mt < 2; ++mt)
                #pragma unroll
                for (int r = 0; r < 4; ++r)
                    sB[wrow + mt * 16 + quad * 4 + r][nt * 16 + l16] = f2s(acc[mt][nt][r]);
        #pragma unroll
        for (int mt = 0; mt < 2; ++mt)
            #pragma unroll
            for (int nt = 0; nt < 8; ++nt) acc[mt][nt] = (v4f){0.f, 0.f, 0.f, 0.f};
        #pragma unroll
        for (int kk = 0; kk < 4; ++kk) {
            v8s a0 = *(const v8s*)&sB[wrow + l16][kk * 32 + quad * 8];
            v8s a1 = *(const v8s*)&sB[wrow + 16 + l16][kk * 32 + quad * 8];
            #pragma unroll
            for (int nt = 0; nt < 8; ++nt) {
                v8s b = *(const v8s*)(W1t + (nt * 16 + l16) * 128 + kk * 32 + quad * 8);
                acc[0][nt] = MFMA(a0, b, acc[0][nt]);
                acc[1][nt] = MFMA(a1, b, acc[1][nt]);
            }
        }
        #pragma unroll
        for (int nt = 0; nt < 8; ++nt) {
            float bb = sP[4 * l + 0][nt * 16 + l16];
            #pragma unroll
            for (int mt = 0; mt < 2; ++mt)
                #pragma unroll
                for (int r = 0; r < 4; ++r)
                    sB[wrow + mt * 16 + quad * 4 + r][nt * 16 + l16] = f2s(fmaxf(acc[mt][nt][r] + bb, 0.f));
        }
        #pragma unroll
        for (int mt = 0; mt < 2; ++mt)
            #pragma unroll
            for (int nt = 0; nt < 8; ++nt) acc[mt][nt] = (v4f){0.f, 0.f, 0.f, 0.f};
        #pragma unroll
        for (int kk = 0; kk < 4; ++kk) {
            v8s a0 = *(const v8s*)&sB[wrow + l16][kk * 32 + quad * 8];
            v8s a1 = *(const v8s*)&sB[wrow + 16 + l16][kk * 32 + quad * 8];
            #pragma unroll
            for (int nt = 0; nt < 8; ++nt) {
                v8s b = *(const v8s*)(W2t + (nt * 16 + l16) * 128 + kk * 32 + quad * 8);
                acc[0][nt] = MFMA(a0, b, acc[0][nt]);
                acc[1][nt] = MFMA(a1, b, acc[1][nt]);
            }
        }
        __syncthreads();
        #pragma unroll
        for (int mt = 0; mt < 2; ++mt)
            #pragma unroll
            for (int r = 0; r < 4; ++r) {
                float s = 0.f, qq = 0.f;
                #pragma unroll
                for (int nt = 0; nt < 8; ++nt) {
                    float u = acc[mt][nt][r] + sP[4 * l + 1][nt * 16 + l16];
                    acc[mt][nt][r] = u;
                    s += u; qq += u * u;
                }
                #pragma unroll
                for (int d = 1; d < 16; d <<= 1) {
                    s += __shfl_xor(s, d);
                    qq += __shfl_xor(qq, d);
                }
                float mn = s * (1.f / 128.f);
                float rs = rsqrtf(qq * (1.f / 128.f) - mn * mn + 1e-5f);
                const int i = wrow + mt * 16 + quad * 4 + r;
                #pragma unroll
                for (int nt = 0; nt < 8; ++nt) {
                    const int n = nt * 16 + l16;
                    float v = fmaxf((acc[mt][nt][r] - mn) * rs * sP[4 * l + 2][n] + sP[4 * l + 3][n], 0.f);
                    float h2 = hs_reg[mt][nt][r] + v;
                    hs_reg[mt][nt][r] = h2;
                    sB[n][i] = f2s(h2);
                }
            }
        __syncthreads();
    }

    float* sRedf = (float*)&sB[0][0];
    #pragma unroll
    for (int nt = 0; nt < 8; ++nt) {
        float part = 0.f;
        #pragma unroll
        for (int mt = 0; mt < 2; ++mt)
            #pragma unroll
            for (int r = 0; r < 4; ++r) part += hs_reg[mt][nt][r];
        sRedf[(wave * 4 + quad) * 128 + nt * 16 + l16] = part;
    }
    __syncthreads();
    if (t < 128) {
        float s = 0.f;
        #pragma unroll
        for (int r = 0; r < 16; ++r) s += sRedf[r * 128 + t];
        hsum[(size_t)b_s * 128 + t] = s;
    }
}

// ---------------- fused tail (passing, R17) ----------------
__global__ __launch_bounds__(128) void k_tail(const float* __restrict__ hsum,
    const float* __restrict__ s2W, const float* __restrict__ s2b,
    const float* __restrict__ rW1, const float* __restrict__ rb1,
    const float* __restrict__ rW2, const float* __restrict__ rb2,
    const float* __restrict__ rg, const float* __restrict__ rbn,
    const float* __restrict__ outW, const float* __restrict__ outb,
    float* __restrict__ out)
{
    __shared__ float sA[16][136];
    __shared__ float sV[128];
    __shared__ float red[128];
    const int g = blockIdx.x, hd = threadIdx.x;
    #pragma unroll
    for (int r = 0; r < 16; ++r) sA[r][hd] = hsum[((size_t)(g * 16 + r)) * 128 + hd];
    __syncthreads();
    float acc[16];
    #pragma unroll
    for (int r = 0; r < 16; ++r) acc[r] = s2b[hd];
    for (int k = 0; k < 128; k += 4) {
        float w0 = s2W[(k+0)*128+hd], w1 = s2W[(k+1)*128+hd], w2 = s2W[(k+2)*128+hd], w3 = s2W[(k+3)*128+hd];
        #pragma unroll
        for (int r = 0; r < 16; ++r) {
            float4 a = *(const float4*)&sA[r][k];
            acc[r] = fmaf(a.x, w0, acc[r]); acc[r] = fmaf(a.y, w1, acc[r]);
            acc[r] = fmaf(a.z, w2, acc[r]); acc[r] = fmaf(a.w, w3, acc[r]);
        }
    }
    float pool = -INFINITY;
    #pragma unroll
    for (int r = 0; r < 16; ++r) pool = fmaxf(pool, fmaxf(acc[r], 0.f));
    sV[hd] = pool;
    __syncthreads();
    float t1 = rb1[hd];
    for (int k = 0; k < 128; ++k) t1 = fmaf(sV[k], rW1[k * 128 + hd], t1);
    t1 = fmaxf(t1, 0.f);
    red[hd] = t1;
    __syncthreads();
    float u = rb2[hd];
    for (int k = 0; k < 128; ++k) u = fmaf(red[k], rW2[k * 128 + hd], u);
    float* rs1 = (float*)&sA[0][0];
    float* rs2 = (float*)&sA[2][0];
    rs1[hd] = u; rs2[hd] = u * u;
    __syncthreads();
    for (int s = 64; s > 0; s >>= 1) {
        if (hd < s) { rs1[hd] += rs1[hd + s]; rs2[hd] += rs2[hd + s]; }
        __syncthreads();
    }
    float mn = rs1[0] * (1.f / 128.f);
    float var = rs2[0] * (1.f / 128.f) - mn * mn;
    float rstd = rsqrtf(var + 1e-5f);
    float p2 = fmaxf((u - mn) * rstd * rg[hd] + rbn[hd], 0.f) + sV[hd];
    __syncthreads();
    red[hd] = p2 * outW[hd];
    __syncthreads();
    for (int s = 64; s > 0; s >>= 1) {
        if (hd < s) red[hd] += red[hd + s];
        __syncthreads();
    }
    if (hd == 0) out[g] = red[0] + outb[0];
}

extern "C" void kernel_launch(void* const* d_in, const int* in_sizes, int n_in,
                              void* d_out, int out_size, void* d_ws, size_t ws_size,
                              hipStream_t stream)
{
    (void)in_sizes; (void)n_in; (void)out_size; (void)ws_size;
    const float* x     = (const float*)d_in[0];
    const float* adj   = (const float*)d_in[1];
    const float* idemb = (const float*)d_in[2];
    const float* in_W1 = (const float*)d_in[3];
    const float* in_b1 = (const float*)d_in[4];
    const float* in_W2 = (const float*)d_in[5];
    const float* in_b2 = (const float*)d_in[6];
    const float* in_g  = (const float*)d_in[7];
    const float* in_bn = (const float*)d_in[8];
    const float* gW1   = (const float*)d_in[9];
    const float* gb1   = (const float*)d_in[10];
    const float* gW2   = (const float*)d_in[11];
    const float* gb2   = (const float*)d_in[12];
    const float* gg    = (const float*)d_in[13];
    const float* gbn   = (const float*)d_in[14];
    const float* iW1   = (const float*)d_in[15];
    const float* ib1   = (const float*)d_in[16];
    const float* iW2   = (const float*)d_in[17];
    const float* ib2   = (const float*)d_in[18];
    const float* ig    = (const float*)d_in[19];
    const float* ibn   = (const float*)d_in[20];
    const float* glW1  = (const float*)d_in[21];
    const float* glb1  = (const float*)d_in[22];
    const float* glW2  = (const float*)d_in[23];
    const float* glb2  = (const float*)d_in[24];
    const float* glg   = (const float*)d_in[25];
    const float* glbn  = (const float*)d_in[26];
    const float* s1_W  = (const float*)d_in[27];
    const float* s1_b  = (const float*)d_in[28];
    const float* s2_W  = (const float*)d_in[29];
    const float* s2_b  = (const float*)d_in[30];
    const float* rW1   = (const float*)d_in[31];
    const float* rb1   = (const float*)d_in[32];
    const float* rW2   = (const float*)d_in[33];
    const float* rb2   = (const float*)d_in[34];
    const float* rg    = (const float*)d_in[35];
    const float* rbn   = (const float*)d_in[36];
    const float* out_W = (const float*)d_in[37];
    const float* out_b = (const float*)d_in[38];
    const int* subgs   = (const int*)d_in[39];
    const int* num_node= (const int*)d_in[41];
    const int* allperm = (const int*)d_in[42];

    // ---- workspace layout (unchanged budget) ----
    const size_t MB_ = (size_t)512 * 128 * P_ * H_ * 2;        // 100,663,296: z2t
    char* w = (char*)d_ws;
    bf16*  mz     = (bf16*)(w);                                // region A: z2t
    bf16*  zm     = (bf16*)(w + MB_);                          // (512,128,128) bf16 = 16.8 MB
    bf16*  WT     = (bf16*)(w + MB_ + 16777216ull);            // 8 x (128x128) bf16 transposed
    char*  wc     = w + MB_ + 16777216ull + 262144ull;
    float* hb     = (float*)(wc);                              // h (32,128,128) f32  2 MB
    bf16*  adjb   = (bf16*)(wc + 2097152ull);                  // 1 MB
    bf16*  WT2    = (bf16*)(wc + 3145728ull);                  // 8 x 32KB = 256 KB
    float* hsum   = (float*)(wc + 4194304ull);                 // (512,128)
    bf16*  s1WtX  = (bf16*)(wc + 4456448ull);                  // s1_W^T bf16 32KB
    float* degf   = (float*)(wc + 4964352ull);                 // 4096 f32
    float* outp   = (float*)d_out;

    // prep: deg+adjb + WT x8 + WT2 x8 + s1Wt  (one dispatch)
    k_prep<<<6272, 128, 0, stream>>>(adj, degf, adjb,
        iW1, iW2, glW1, glW2, in_W2, gW1, gW2, s1_W,
        WT, WT2, s1WtX);

    // h pipeline fused: input embed + 3 g-layers -> hb
    k_h_fused<<<32, 256, 0, stream>>>(x, adjb, in_W1, in_b1,
        WT2, in_b2, in_g, in_bn,
        WT2 + 16384, gb1, gb2, gg, gbn, hb);

    // ID layer 1 FUSED (single-buffer): m in-LDS -> MFMA MLP -> z2t
    k_id1_fused<<<3072, 256, 0, stream>>>(adj, degf, subgs, allperm, idemb, mz,
        WT, ib1, WT + 16384, ib2, ig, ibn);

    // ID layer 2 v9 -> zm
    k_id2_v9<<<512, 256, 0, stream>>>(mz, zm, adjb, num_node, subgs, allperm, idemb,
        WT + 2 * 16384, ib1 + 128, WT + 3 * 16384, ib2 + 128, ig + 128, ibn + 128);

    // fused gl v2 (single-buffer): setmlp1 + 2 gl layers + node-sum -> hsum
    k_gl_fused<<<512, 256, 0, stream>>>(zm, hb, adjb, s1WtX, s1_b,
        WT + 4 * 16384, glb1, glb2, glg, glbn, hsum);

    // fused tail: setmlp2 + maxpool + setmlp3 + out proj
    k_tail<<<32, 128, 0, stream>>>(hsum, s2_W, s2_b, rW1, rb1, rW2, rb2,
        rg, rbn, out_W, out_b, outp);
}